// Round 1
// baseline (1198.011 us; speedup 1.0000x reference)
//
#include <hip/hip_runtime.h>

// LSTM: B=512, T=1000, IN=39, H=64, OUT=48, gate order i,f,g,o.
// One block per batch row; thread = gate index (4H=256 threads).
// Weights register-resident; h/x/act via LDS broadcast; 3 barriers/step.

#define BB 512
#define TT 1000
#define INF 39
#define HH 64
#define OUTF 48
#define G4 (4 * HH)

__global__ __launch_bounds__(256, 2) void lstm_fused_kernel(
    const float* __restrict__ x,      // [B,T,IN]
    const float* __restrict__ W_ih,   // [4H, IN]
    const float* __restrict__ W_hh,   // [4H, H]
    const float* __restrict__ b_ih,   // [4H]
    const float* __restrict__ b_hh,   // [4H]
    const float* __restrict__ W_out,  // [OUT, H]
    const float* __restrict__ b_out,  // [OUT]
    float* __restrict__ out)          // [B,T,OUT]
{
    const int b = blockIdx.x;
    const int tid = threadIdx.x;          // gate index g in [0,256)

    __shared__ float xs[INF];             // x_t broadcast
    __shared__ float hs[HH];              // h_t broadcast
    __shared__ float act[G4];             // gate activations

    // ---- one-time: weights into registers ----
    float wih[INF];
#pragma unroll
    for (int i = 0; i < INF; ++i) wih[i] = W_ih[tid * INF + i];
    float whh[HH];
#pragma unroll
    for (int k = 0; k < HH; ++k) whh[k] = W_hh[tid * HH + k];
    const float bias = b_ih[tid] + b_hh[tid];

    // output-projection slice: thread tid<192 -> (o = tid>>2, p = tid&3)
    const int o = tid >> 2;
    const int p = tid & 3;
    float wout[16];
    float bo = 0.f;
    if (tid < 4 * OUTF) {
#pragma unroll
        for (int k = 0; k < 16; ++k) wout[k] = W_out[o * HH + p * 16 + k];
        bo = b_out[o];
    }

    float c = 0.f;                        // cell state, owned by tid<64
    if (tid < HH) hs[tid] = 0.f;
    float xreg = (tid < INF) ? x[(size_t)b * TT * INF + tid] : 0.f;

    const int gate_type = tid >> 6;       // wave-uniform: 0=i,1=f,2=g,3=o
    const size_t out_base = (size_t)b * TT * OUTF;
    const size_t x_base = (size_t)b * TT * INF;

    for (int t = 0; t < TT; ++t) {
        if (tid < INF) xs[tid] = xreg;
        __syncthreads();                  // xs, hs ready
        if (tid < INF && t + 1 < TT) xreg = x[x_base + (size_t)(t + 1) * INF + tid];

        // gate pre-activation
        float acc = bias;
#pragma unroll
        for (int i = 0; i < INF; ++i) acc += xs[i] * wih[i];
#pragma unroll
        for (int k = 0; k < HH; ++k) acc += hs[k] * whh[k];

        float a;
        if (gate_type == 2) {             // tanh for g-gate (wave-uniform branch)
            a = 2.f / (1.f + __expf(-2.f * acc)) - 1.f;
        } else {                          // sigmoid for i,f,o
            a = 1.f / (1.f + __expf(-acc));
        }
        act[tid] = a;
        __syncthreads();                  // act ready

        if (tid < HH) {
            const float ig = act[tid];
            const float fg = act[HH + tid];
            const float gg = act[2 * HH + tid];
            const float og = act[3 * HH + tid];
            c = fg * c + ig * gg;
            const float th = 2.f / (1.f + __expf(-2.f * c)) - 1.f;
            hs[tid] = og * th;
        }
        __syncthreads();                  // new h ready

        if (tid < 4 * OUTF) {
            float s = 0.f;
#pragma unroll
            for (int k = 0; k < 16; ++k) s += hs[p * 16 + k] * wout[k];
            s += __shfl_xor(s, 1, 64);
            s += __shfl_xor(s, 2, 64);
            if (p == 0) {
                const float y = 1.f / (1.f + __expf(-(s + bo)));
                out[out_base + (size_t)t * OUTF + o] = y;
            }
        }
    }
}

extern "C" void kernel_launch(void* const* d_in, const int* in_sizes, int n_in,
                              void* d_out, int out_size, void* d_ws, size_t ws_size,
                              hipStream_t stream) {
    const float* x     = (const float*)d_in[0];
    const float* W_ih  = (const float*)d_in[1];
    const float* W_hh  = (const float*)d_in[2];
    const float* b_ih  = (const float*)d_in[3];
    const float* b_hh  = (const float*)d_in[4];
    const float* W_out = (const float*)d_in[5];
    const float* b_out = (const float*)d_in[6];
    float* out = (float*)d_out;

    lstm_fused_kernel<<<dim3(BB), dim3(G4), 0, stream>>>(
        x, W_ih, W_hh, b_ih, b_hh, W_out, b_out, out);
}

// Round 3
// 1075.008 us; speedup vs baseline: 1.1144x; 1.1144x over previous
//
#include <hip/hip_runtime.h>

// LSTM: B=512, T=1000, IN=39, H=64, OUT=48, gate order i,f,g,o.
// One block per batch row; thread = gate index (4H=256 threads).
// R2: weights as macro-generated NAMED registers (R1's arrays were scratch-
// demoted at VGPR_Count=80 -> every step re-streamed ~105KB/block from L2).
// R3: fix x-prefetch off-by-one (R2 consumed x_{t-1} from t>=2: staging takes
// x_{t+1} from xreg, so the refill must load x_{t+2}, not x_{t+1}).

#define BB 512
#define TT 1000
#define INF 39
#define HH 64
#define OUTF 48
#define G4 (4 * HH)

// ---- repeat lists ----
#define Q10(M) M(0) M(1) M(2) M(3) M(4) M(5) M(6) M(7) M(8) M(9)
#define Q16(M) M(0) M(1) M(2) M(3) M(4) M(5) M(6) M(7) \
               M(8) M(9) M(10) M(11) M(12) M(13) M(14) M(15)

__global__ __launch_bounds__(256, 2) void lstm_fused_kernel(
    const float* __restrict__ x,      // [B,T,IN]
    const float* __restrict__ W_ih,   // [4H, IN]
    const float* __restrict__ W_hh,   // [4H, H]
    const float* __restrict__ b_ih,   // [4H]
    const float* __restrict__ b_hh,   // [4H]
    const float* __restrict__ W_out,  // [OUT, H]
    const float* __restrict__ b_out,  // [OUT]
    float* __restrict__ out)          // [B,T,OUT]
{
    const int b = blockIdx.x;
    const int tid = threadIdx.x;          // gate index in [0,256)

    __shared__ float xs[40];              // x_t broadcast (padded, xs[39]=0)
    __shared__ float hs[HH];              // h_t broadcast
    __shared__ float act[G4];             // gate activations

    // ---- one-time: weights into NAMED registers ----
    const float* wih_ptr = W_ih + tid * INF;
    // 10 quads covering 40 (last lane zero-padded)
#define LOAD_IH4(q) float4 wiq##q; \
    wiq##q.x = wih_ptr[4*(q)]; \
    wiq##q.y = (4*(q)+1 < INF) ? wih_ptr[4*(q)+1] : 0.f; \
    wiq##q.z = (4*(q)+2 < INF) ? wih_ptr[4*(q)+2] : 0.f; \
    wiq##q.w = (4*(q)+3 < INF) ? wih_ptr[4*(q)+3] : 0.f;
    Q10(LOAD_IH4)

    const float4* wh4p = (const float4*)(W_hh + tid * HH);  // 256B-aligned
#define LOAD_HH4(i) const float4 wh##i = wh4p[i];
    Q16(LOAD_HH4)

    const float bias = b_ih[tid] + b_hh[tid];

    // output-projection slice: tid<192 -> (o = tid>>2, p = tid&3), 16 wts
    const int o = tid >> 2;
    const int p = tid & 3;
    float4 wo0, wo1, wo2, wo3;
    float bo = 0.f;
    if (tid < 4 * OUTF) {
        const float4* wop = (const float4*)(W_out + o * HH + p * 16); // 64B-aligned
        wo0 = wop[0]; wo1 = wop[1]; wo2 = wop[2]; wo3 = wop[3];
        bo = b_out[o];
    } else {
        wo0 = wo1 = wo2 = wo3 = make_float4(0.f, 0.f, 0.f, 0.f);
    }

    float c = 0.f;                        // cell state, owned by tid<64
    const size_t x_base = (size_t)b * TT * INF;
    const size_t out_base = (size_t)b * TT * OUTF;

    if (tid < HH) hs[tid] = 0.f;
    if (tid < INF) xs[tid] = x[x_base + tid];
    if (tid == 39) xs[39] = 0.f;
    float xreg = (tid < INF) ? x[x_base + INF + tid] : 0.f;  // prefetch x_1

    const int gate_type = tid >> 6;       // wave-uniform: 0=i,1=f,2=g,3=o
    __syncthreads();                      // xs=x_0, hs=0 ready

    const float4* xs4 = (const float4*)xs;
    const float4* hs4 = (const float4*)hs;

    for (int t = 0; t < TT; ++t) {
        // ---- gate pre-activation: acc = bias + x.Wih_row + h.Whh_row ----
        float a0 = bias, a1 = 0.f, a2 = 0.f, a3 = 0.f;
#define FMA_IH4(q) { const float4 xv = xs4[q]; \
        a0 += xv.x * wiq##q.x; a1 += xv.y * wiq##q.y; \
        a2 += xv.z * wiq##q.z; a3 += xv.w * wiq##q.w; }
        Q10(FMA_IH4)
#define FMA_HH4(i) { const float4 hv = hs4[i]; \
        a0 += hv.x * wh##i.x; a1 += hv.y * wh##i.y; \
        a2 += hv.z * wh##i.z; a3 += hv.w * wh##i.w; }
        Q16(FMA_HH4)
        const float acc = (a0 + a1) + (a2 + a3);

        float a;
        if (gate_type == 2) {             // tanh (wave-uniform branch)
            a = 2.f / (1.f + __expf(-2.f * acc)) - 1.f;
        } else {                          // sigmoid
            a = 1.f / (1.f + __expf(-acc));
        }
        act[tid] = a;
        __syncthreads();                  // A: act ready; xs/hs reads done

        // stage x_{t+1}; refill prefetch with x_{t+2} (consumed after barrier B)
        if (tid < INF) {
            xs[tid] = xreg;
            if (t + 2 < TT) xreg = x[x_base + (size_t)(t + 2) * INF + tid];
        }
        if (tid < HH) {
            const float ig = act[tid];
            const float fg = act[HH + tid];
            const float gg = act[2 * HH + tid];
            const float og = act[3 * HH + tid];
            c = fg * c + ig * gg;
            const float th = 2.f / (1.f + __expf(-2.f * c)) - 1.f;
            hs[tid] = og * th;
        }
        __syncthreads();                  // B: hs = h_t, xs = x_{t+1}

        // ---- output projection y_t = sigmoid(h_t . W_out_row + b) ----
        if (tid < 4 * OUTF) {
            const float4 h0 = hs4[p * 4 + 0];
            const float4 h1 = hs4[p * 4 + 1];
            const float4 h2 = hs4[p * 4 + 2];
            const float4 h3 = hs4[p * 4 + 3];
            float s0 = h0.x * wo0.x + h0.y * wo0.y + h0.z * wo0.z + h0.w * wo0.w;
            float s1 = h1.x * wo1.x + h1.y * wo1.y + h1.z * wo1.z + h1.w * wo1.w;
            float s2 = h2.x * wo2.x + h2.y * wo2.y + h2.z * wo2.z + h2.w * wo2.w;
            float s3 = h3.x * wo3.x + h3.y * wo3.y + h3.z * wo3.z + h3.w * wo3.w;
            float s = (s0 + s1) + (s2 + s3);
            s += __shfl_xor(s, 1, 64);
            s += __shfl_xor(s, 2, 64);
            if (p == 0) {
                const float y = 1.f / (1.f + __expf(-(s + bo)));
                __builtin_nontemporal_store(y, &out[out_base + (size_t)t * OUTF + o]);
            }
        }
    }
}

extern "C" void kernel_launch(void* const* d_in, const int* in_sizes, int n_in,
                              void* d_out, int out_size, void* d_ws, size_t ws_size,
                              hipStream_t stream) {
    const float* x     = (const float*)d_in[0];
    const float* W_ih  = (const float*)d_in[1];
    const float* W_hh  = (const float*)d_in[2];
    const float* b_ih  = (const float*)d_in[3];
    const float* b_hh  = (const float*)d_in[4];
    const float* W_out = (const float*)d_in[5];
    const float* b_out = (const float*)d_in[6];
    float* out = (float*)d_out;

    lstm_fused_kernel<<<dim3(BB), dim3(G4), 0, stream>>>(
        x, W_ih, W_hh, b_ih, b_hh, W_out, b_out, out);
}